// Round 8
// baseline (98.731 us; speedup 1.0000x reference)
//
#include <hip/hip_runtime.h>
#include <math.h>

// DistanceLoss — y_pred (8,2,512,512) f32, y_true (8,2,512,512) f32 -> scalar f32.
// loss = mean[(1 + EDT(y_true)/511) * (softmax(y_pred,C=2) - y_true)^2]
// Fully fused: one block = one (img, 16-row stripe); row-pass halo recomputed
// into LDS, windowed exact column pass, loss epilogue, last-block reduction.

#define H 512
#define W 512
#define NIMG 16            // N*C
#define HW (H * W)
#define RW 5               // exact window radius (certified + exact fallback)
#define SEG 16             // output rows per block
#define HALO (SEG + 2*RW)  // 26 halo rows
#define NBLK (NIMG * (H / SEG))   // 512 blocks

__global__ __launch_bounds__(512) void fused_loss_kernel(
        const float* __restrict__ yp, const float* __restrict__ yt,
        double* __restrict__ part, unsigned int* __restrict__ counter,
        float* __restrict__ out) {
    __shared__ float lw[HALO][W];      // 53.25 KB halo of d1sq
    __shared__ double wsum[8];
    __shared__ int fb;
    __shared__ int lastf;

    const int tid  = threadIdx.x;
    const int wv   = tid >> 6;
    const int lane = tid & 63;
    const int img  = blockIdx.y;            // 0..15
    const int i0   = blockIdx.x * SEG;      // first output row
    const int bid  = blockIdx.y * gridDim.x + blockIdx.x;

    const float BIG = 3.0e38f;
    const float INF = 1024.0f;              // H + W, matches reference
    const float* ytimg = yt + (size_t)img * HW;

    if (tid == 0) fb = 0;

    // ---- Phase 1: row-pass (1D width distance squared) for 26 halo rows ----
    for (int r = wv; r < HALO; r += 8) {
        int ip = i0 - RW + r;
        int k0 = lane * 8;
        if (ip >= 0 && ip < H) {
            const float* rp = ytimg + ip * W;
            float4 va = *reinterpret_cast<const float4*>(rp + k0);
            float4 vb = *reinterpret_cast<const float4*>(rp + k0 + 4);
            float g[8] = { va.x, va.y, va.z, va.w, vb.x, vb.y, vb.z, vb.w };
            #pragma unroll
            for (int t = 0; t < 8; ++t) g[t] = (g[t] > 0.5f) ? 0.0f : INF;

            float pm[8], sm[8];
            float run = BIG;
            #pragma unroll
            for (int t = 0; t < 8; ++t) {
                run = fminf(run, g[t] - (float)(k0 + t));
                pm[t] = run;
            }
            float incl = run;
            #pragma unroll
            for (int d = 1; d < 64; d <<= 1) {
                float o = __shfl_up(incl, d);
                if (lane >= d) incl = fminf(incl, o);
            }
            float excl = __shfl_up(incl, 1);
            if (lane == 0) excl = BIG;

            run = BIG;
            #pragma unroll
            for (int t = 7; t >= 0; --t) {
                run = fminf(run, g[t] + (float)(k0 + t));
                sm[t] = run;
            }
            float incl2 = run;
            #pragma unroll
            for (int d = 1; d < 64; d <<= 1) {
                float o = __shfl_down(incl2, d);
                if (lane < 64 - d) incl2 = fminf(incl2, o);
            }
            float excl2 = __shfl_down(incl2, 1);
            if (lane == 63) excl2 = BIG;

            float o8[8];
            #pragma unroll
            for (int t = 0; t < 8; ++t) {
                float kf = (float)(k0 + t);
                float f = kf + fminf(excl, pm[t]);
                float b = -kf + fminf(excl2, sm[t]);
                float d = fminf(f, b);
                o8[t] = d * d;               // exact integer in fp32
            }
            *reinterpret_cast<float4*>(&lw[r][k0])     = make_float4(o8[0], o8[1], o8[2], o8[3]);
            *reinterpret_cast<float4*>(&lw[r][k0 + 4]) = make_float4(o8[4], o8[5], o8[6], o8[7]);
        } else {
            float4 b4 = make_float4(BIG, BIG, BIG, BIG);
            *reinterpret_cast<float4*>(&lw[r][k0])     = b4;
            *reinterpret_cast<float4*>(&lw[r][k0 + 4]) = b4;
        }
    }
    __syncthreads();

    // ---- Phase 2: windowed exact column pass (constants (RW-k)^2) ----
    const int j = tid;                       // one column per thread
    float wsq[HALO];
    #pragma unroll
    for (int k = 0; k < HALO; ++k) wsq[k] = lw[k][j];

    const float C2[2 * RW + 1] = {25.f,16.f,9.f,4.f,1.f,0.f,1.f,4.f,9.f,16.f,25.f};
    float mn[SEG];
    #pragma unroll
    for (int m = 0; m < SEG; ++m) {
        float v = wsq[m] + C2[0];
        #pragma unroll
        for (int k = 1; k < 2 * RW + 1; ++k)
            v = fminf(v, wsq[m + k] + C2[k]);
        mn[m] = v;
    }

    // certification: if every mn <= (RW+1)^2 the window min is the global min
    bool need = false;
    const float thr = (float)((RW + 1) * (RW + 1));
    #pragma unroll
    for (int m = 0; m < SEG; ++m) need |= (mn[m] > thr);
    if (__any(need) && lane == 0) atomicOr(&fb, 1);
    __syncthreads();

    if (fb) {   // exact full-column fallback (dead for this input, exact always)
        for (int base = 0; base < H; base += HALO) {
            int rows = (H - base < HALO) ? (H - base) : HALO;
            __syncthreads();
            for (int r = wv; r < rows; r += 8) {
                int ip = base + r;
                int k0 = lane * 8;
                const float* rp = ytimg + ip * W;
                float4 va = *reinterpret_cast<const float4*>(rp + k0);
                float4 vb = *reinterpret_cast<const float4*>(rp + k0 + 4);
                float g[8] = { va.x, va.y, va.z, va.w, vb.x, vb.y, vb.z, vb.w };
                #pragma unroll
                for (int t = 0; t < 8; ++t) g[t] = (g[t] > 0.5f) ? 0.0f : INF;
                float pm[8], sm[8];
                float run = BIG;
                #pragma unroll
                for (int t = 0; t < 8; ++t) {
                    run = fminf(run, g[t] - (float)(k0 + t));
                    pm[t] = run;
                }
                float incl = run;
                #pragma unroll
                for (int d = 1; d < 64; d <<= 1) {
                    float o = __shfl_up(incl, d);
                    if (lane >= d) incl = fminf(incl, o);
                }
                float excl = __shfl_up(incl, 1);
                if (lane == 0) excl = BIG;
                run = BIG;
                #pragma unroll
                for (int t = 7; t >= 0; --t) {
                    run = fminf(run, g[t] + (float)(k0 + t));
                    sm[t] = run;
                }
                float incl2 = run;
                #pragma unroll
                for (int d = 1; d < 64; d <<= 1) {
                    float o = __shfl_down(incl2, d);
                    if (lane < 64 - d) incl2 = fminf(incl2, o);
                }
                float excl2 = __shfl_down(incl2, 1);
                if (lane == 63) excl2 = BIG;
                #pragma unroll
                for (int t = 0; t < 8; ++t) {
                    float kf = (float)(k0 + t);
                    float f = kf + fminf(excl, pm[t]);
                    float b = -kf + fminf(excl2, sm[t]);
                    float d = fminf(f, b);
                    lw[r][k0 + t] = d * d;
                }
            }
            __syncthreads();
            for (int k = 0; k < rows; ++k) {
                int ip = base + k;
                float w = lw[k][j];
                #pragma unroll
                for (int m = 0; m < SEG; ++m) {
                    int d = (i0 + m) - ip;
                    mn[m] = fminf(mn[m], w + (float)(d * d));
                }
            }
        }
    }

    // ---- Phase 3: loss epilogue (identical math to validated version) ----
    const int n = img >> 1;
    const int c = img & 1;
    const float* ypc = yp + (size_t)(n * 2 + c) * HW;
    const float* ypo = yp + (size_t)(n * 2 + (1 - c)) * HW;
    const float* ytc = yt + (size_t)img * HW;

    double local = 0.0;
    #pragma unroll
    for (int m = 0; m < SEG; ++m) {
        int i = i0 + m;
        int idx = i * W + j;
        float dmv = sqrtf(mn[m]) / 511.0f;
        float x0 = ypc[idx], x1 = ypo[idx];
        float mx = fmaxf(x0, x1);
        float e0 = expf(x0 - mx), e1 = expf(x1 - mx);
        float p  = e0 / (e0 + e1);
        float df = p - ytc[idx];
        local += (double)((1.0f + dmv) * (df * df));
    }

    #pragma unroll
    for (int d = 32; d > 0; d >>= 1) local += __shfl_down(local, d);
    if (lane == 0) wsum[wv] = local;
    __syncthreads();

    if (tid == 0) {
        double s = 0.0;
        #pragma unroll
        for (int q = 0; q < 8; ++q) s += wsum[q];
        __hip_atomic_store(&part[bid], s, __ATOMIC_RELEASE, __HIP_MEMORY_SCOPE_AGENT);
        unsigned int old = __hip_atomic_fetch_add(counter, 1u, __ATOMIC_ACQ_REL,
                                                  __HIP_MEMORY_SCOPE_AGENT);
        lastf = (old == NBLK - 1) ? 1 : 0;
    }
    __syncthreads();

    // ---- Phase 4: last block reduces the 512 partials and writes out ----
    if (lastf) {
        double v = __hip_atomic_load(&part[tid], __ATOMIC_ACQUIRE,
                                     __HIP_MEMORY_SCOPE_AGENT);
        #pragma unroll
        for (int d = 32; d > 0; d >>= 1) v += __shfl_down(v, d);
        if (lane == 0) wsum[wv] = v;
        __syncthreads();
        if (tid == 0) {
            double s = 0.0;
            #pragma unroll
            for (int q = 0; q < 8; ++q) s += wsum[q];
            out[0] = (float)(s / (double)(NIMG * HW));
        }
    }
}

extern "C" void kernel_launch(void* const* d_in, const int* in_sizes, int n_in,
                              void* d_out, int out_size, void* d_ws, size_t ws_size,
                              hipStream_t stream) {
    const float* y_pred = (const float*)d_in[0];
    const float* y_true = (const float*)d_in[1];
    float* out = (float*)d_out;

    unsigned int* counter = (unsigned int*)d_ws;
    double* part = (double*)((char*)d_ws + 4096);      // 512 doubles

    hipMemsetAsync(d_ws, 0, 4, stream);                // zero the arrival counter
    fused_loss_kernel<<<dim3(H / SEG, NIMG), 512, 0, stream>>>(
        y_pred, y_true, part, counter, out);
}